// Round 7
// baseline (204.635 us; speedup 1.0000x reference)
//
#include <hip/hip_runtime.h>
#include <hip/hip_bf16.h>

#define NV 16384
#define NC 16
#define NL 6
#define ND 64

typedef unsigned short u16;
typedef unsigned int u32;
typedef __attribute__((ext_vector_type(8))) short short8;
typedef __attribute__((ext_vector_type(4))) float f32x4;

// ---- pbuf (fp32) offsets, pbuf = (float*)((char*)ws + 256) ----
#define PB_BN  0
#define PB_FE  64
#define PB_B1V 128
#define PB_B2V 192
#define PB_B1C 256
#define PB_B2C 320
// ---- bf16 regions, offsets in u16 elements from (u16*)ws ----
#define U_BV    896       // [128][384]  Bv[n][k]: n<64 -> W1v[k][n], n>=64 -> W2v[k][n-64]
#define U_BC    50048     // [128][1024] same for W1c/W2c
#define U_BN    181120    // [64][64]    Bn[n][k] = Wn[k][n]
#define U_VARSB 185216    // [NV+1][64]  bf16 vars; row NV = false_emb
#define U_NEGB  1233856   // [NV+1][64]  bf16 negvar; row NV = true_emb
#define U_CE    2282496   // [NV][16][64] bf16 clause_emb
#define U_FIDX  19059712  // [NV][96] u16 fused row index into unified vars/neg table

__device__ __forceinline__ float ldbf(const u16* p, int i) {
  return __uint_as_float(((u32)p[i]) << 16);
}
__device__ __forceinline__ u16 f2b(float f) {  // RNE f32->bf16
  u32 x = __float_as_uint(f);
  return (u16)((x + 0x7FFF + ((x >> 16) & 1)) >> 16);
}
__device__ __forceinline__ int ldmask(const void* p, int i, int bdt) {
  return bdt ? (int)((const signed char*)p)[i] : ((const int*)p)[i];
}
__device__ __forceinline__ float ldf(const void* p, int i, int fdt) {
  return fdt ? ldbf((const u16*)p, i) : ((const float*)p)[i];
}

// ---------- merged prep: sniff (per-block) + params + W transpose + cvt + fidx ----------
__global__ __launch_bounds__(256) void k_prep(
    const void* vars, const int* __restrict__ lits, const void* negm, const void* vval,
    const void* Wn, const void* bn, const void* femb,
    const void* W1v, const void* b1v, const void* W2v, const void* b2v,
    const void* W1c, const void* b1c, const void* W2c, const void* b2c,
    int* flags, float* pbuf, u16* wsB) {
  __shared__ int s_cnt[4], s_big[4];
  const int t = threadIdx.x;
  {
    const u32 w = ((const u32*)vars)[t];
    const u32 e = (w >> 7) & 0xFF;
    const unsigned long long bal = __ballot(e >= 0x6E && e <= 0x8E);
    const u32 bw = ((const u32*)vval)[t];
    const unsigned long long bb = __ballot(bw > 1u);
    if ((t & 63) == 0) { s_cnt[t >> 6] = __popcll(bal); s_big[t >> 6] = (bb != 0ull); }
  }
  __syncthreads();
  const int fdt = (s_cnt[0] + s_cnt[1] + s_cnt[2] + s_cnt[3]) >= 192;
  const int bdt = (s_big[0] | s_big[1] | s_big[2] | s_big[3]);
  const int bid = blockIdx.x;

  if (bid == 0) {
    if (t == 0) { flags[0] = fdt; flags[1] = bdt; }
    if (t < 64) {
      const void* src[6] = {bn, femb, b1v, b2v, b1c, b2c};
      const int off[6] = {PB_BN, PB_FE, PB_B1V, PB_B2V, PB_B1C, PB_B2C};
      for (int j = 0; j < 6; j++) pbuf[off[j] + t] = ldf(src[j], t, fdt);
      wsB[U_VARSB + NV * 64 + t] = fdt ? ((const u16*)femb)[t] : f2b(((const float*)femb)[t]);
    }
  } else if (bid < 65) {
    for (int i = (bid - 1) * 256 + t; i < 184320; i += 64 * 256) {
      if (i < 49152) {
        int n = i / 384, k = i - n * 384;
        const void* src = (n < 64) ? W1v : W2v;
        wsB[U_BV + i] = f2b(ldf(src, k * 64 + (n & 63), fdt));
      } else if (i < 180224) {
        int j = i - 49152;
        int n = j / 1024, k = j - n * 1024;
        const void* src = (n < 64) ? W1c : W2c;
        wsB[U_BC + j] = f2b(ldf(src, k * 64 + (n & 63), fdt));
      } else {
        int j = i - 180224;
        int n = j >> 6, k = j & 63;
        wsB[U_BN + j] = f2b(ldf(Wn, k * 64 + n, fdt));
      }
    }
  } else if (bid < 577) {
    const int c8 = (bid - 65) * 256 + t;
    u16 o[8];
    if (fdt) {
      *(short8*)o = ((const short8*)vars)[c8];
    } else {
      const float* f = (const float*)vars + c8 * 8;
#pragma unroll
      for (int j = 0; j < 8; j++) o[j] = f2b(f[j]);
    }
    *(short8*)(wsB + U_VARSB + c8 * 8) = *(short8*)o;
  } else {
    const int i0 = ((bid - 577) * 256 + t) * 4;
    u16 o[4];
#pragma unroll
    for (int j = 0; j < 4; j++) {
      const int i = i0 + j;
      const int valid = ldmask(vval, i, bdt);
      const int neg = ldmask(negm, i, bdt);
      const int idx = lits[i];
      o[j] = (u16)(valid ? (idx + (neg ? (NV + 1) : 0)) : NV);
    }
    *(ushort4*)(wsB + U_FIDX + i0) = *(ushort4*)o;
  }
}

// ---------- negvar via MFMA ----------
__global__ __launch_bounds__(256) void k_negvar(const float* pbuf, u16* wsB) {
  const int tid = threadIdx.x, lane = tid & 63, wv = tid >> 6;
  const int col = lane & 15, quad = lane >> 4, q8 = quad * 8;
  const int rowbase = blockIdx.x * 64 + wv * 16;
  f32x4 acc[4];
#pragma unroll
  for (int nt = 0; nt < 4; nt++) acc[nt] = (f32x4){0.f, 0.f, 0.f, 0.f};
  const int arow = min(rowbase + col, NV);
#pragma unroll
  for (int ks = 0; ks < 2; ks++) {
    const short8 a = *(const short8*)(wsB + U_VARSB + arow * 64 + ks * 32 + q8);
#pragma unroll
    for (int nt = 0; nt < 4; nt++) {
      const short8 b = *(const short8*)(wsB + U_BN + (nt * 16 + col) * 64 + ks * 32 + q8);
      acc[nt] = __builtin_amdgcn_mfma_f32_16x16x32_bf16(a, b, acc[nt], 0, 0, 0);
    }
  }
#pragma unroll
  for (int reg = 0; reg < 4; reg++) {
    const int r = rowbase + quad * 4 + reg;
    if (r <= NV) {
#pragma unroll
      for (int nt = 0; nt < 4; nt++) {
        const int d = nt * 16 + col;
        wsB[U_NEGB + r * 64 + d] = f2b(acc[nt][reg] + pbuf[PB_BN + d]);
      }
    }
  }
}

// ---------- clause combiner: double-buffered K-quarter LDS staging + A pipeline ----------
// 256 threads (4 waves), 4 vars/wave = 16 vars/block. 2 blocks/CU.
__global__ __launch_bounds__(256) void k_clause(
    const void* __restrict__ cval, const float* __restrict__ pbuf,
    const int* __restrict__ flags, u16* __restrict__ wsB) {
  __shared__ __align__(16) u16 Bq[2][128 * 104];  // [buf][n][96+8 pad] = 53,248 B

  const int tid = threadIdx.x, lane = tid & 63, wv = tid >> 6;
  const int col = lane & 15, quad = lane >> 4, q8 = quad * 8;
  const int bdt = flags[1];
  const int vbase = (blockIdx.x * 4 + wv) * 4;  // 4 vars per wave

  // gather row indices r_[p][u][l]
  int r_[2][2][6];
#pragma unroll
  for (int p = 0; p < 2; p++)
#pragma unroll
    for (int u = 0; u < 2; u++) {
      const int v = vbase + p * 2 + u;
#pragma unroll
      for (int l = 0; l < 6; l++) r_[p][u][l] = wsB[U_FIDX + v * 96 + col * 6 + l];
    }

  // clause-valid: 64 lanes <-> 4 vars x 16 clauses
  const int cv = ldmask(cval, vbase * 16 + lane, bdt);
  const unsigned long long bal = __ballot(cv != 0);

  f32x4 acc[2][2][8];
#pragma unroll
  for (int p = 0; p < 2; p++)
#pragma unroll
    for (int u = 0; u < 2; u++)
#pragma unroll
      for (int nt = 0; nt < 8; nt++) acc[p][u][nt] = (f32x4){0.f, 0.f, 0.f, 0.f};

  // initial stage: quarter 0 -> buf 0 (6 chunks/thread; 1536 chunks of 8 u16)
  {
    short8 stg[6];
#pragma unroll
    for (int j = 0; j < 6; j++) {
      const int c = j * 256 + tid;
      const int n = c / 12, c8 = c - n * 12;
      stg[j] = *(const short8*)(wsB + U_BV + n * 384 + c8 * 8);
    }
#pragma unroll
    for (int j = 0; j < 6; j++) {
      const int c = j * 256 + tid;
      const int n = c / 12, c8 = c - n * 12;
      *(short8*)(&Bq[0][n * 104 + c8 * 8]) = stg[j];
    }
  }
  __syncthreads();

  // A-fragment pipeline registers: [parity][p][u]
  short8 areg[2][2][2];
#pragma unroll
  for (int p = 0; p < 2; p++)
#pragma unroll
    for (int u = 0; u < 2; u++)
      areg[0][p][u] = *(const short8*)(wsB + U_VARSB + r_[p][u][0] * 64 + q8);

#pragma unroll
  for (int q = 0; q < 4; q++) {
    // issue global loads for quarter q+1 (in flight during compute)
    short8 stg[6];
    if (q < 3) {
#pragma unroll
      for (int j = 0; j < 6; j++) {
        const int c = j * 256 + tid;
        const int n = c / 12, c8 = c - n * 12;
        stg[j] = *(const short8*)(wsB + U_BV + n * 384 + (q + 1) * 96 + c8 * 8);
      }
    }
#pragma unroll
    for (int ks = 0; ks < 3; ks++) {
      const int gk = q * 3 + ks;
      const int cb = gk & 1, nb = cb ^ 1;
      if (gk < 11) {
        const int gl = (gk + 1) >> 1;
        const int goff = ((gk + 1) & 1) * 32 + q8;
#pragma unroll
        for (int p = 0; p < 2; p++)
#pragma unroll
          for (int u = 0; u < 2; u++)
            areg[nb][p][u] = *(const short8*)(wsB + U_VARSB + r_[p][u][gl] * 64 + goff);
      }
#pragma unroll
      for (int nt = 0; nt < 8; nt++) {
        const short8 b = *(const short8*)(&Bq[q & 1][(nt * 16 + col) * 104 + ks * 32 + q8]);
#pragma unroll
        for (int p = 0; p < 2; p++)
#pragma unroll
          for (int u = 0; u < 2; u++)
            acc[p][u][nt] = __builtin_amdgcn_mfma_f32_16x16x32_bf16(areg[cb][p][u], b, acc[p][u][nt], 0, 0, 0);
      }
    }
    if (q < 3) {
#pragma unroll
      for (int j = 0; j < 6; j++) {
        const int c = j * 256 + tid;
        const int n = c / 12, c8 = c - n * 12;
        *(short8*)(&Bq[(q + 1) & 1][n * 104 + c8 * 8]) = stg[j];
      }
      __syncthreads();
    }
  }

  // epilogue
  float b1l[4], b2l[4], truel[4];
#pragma unroll
  for (int nt = 0; nt < 4; nt++) {
    const int d = nt * 16 + col;
    b1l[nt] = pbuf[PB_B1V + d];
    b2l[nt] = pbuf[PB_B2V + d];
    truel[nt] = ldbf(wsB, U_NEGB + NV * 64 + d);
  }
#pragma unroll
  for (int p = 0; p < 2; p++)
#pragma unroll
    for (int u = 0; u < 2; u++) {
      const int v = vbase + p * 2 + u;
      const u32 vmask = (u32)((bal >> ((p * 2 + u) * 16)) & 0xFFFFull);
#pragma unroll
      for (int reg = 0; reg < 4; reg++) {
        const int c = quad * 4 + reg;
        float h[4], ss = 0.f;
#pragma unroll
        for (int nt = 0; nt < 4; nt++) {
          h[nt] = 1.0f / (1.0f + __expf(-(acc[p][u][nt][reg] + b1l[nt]))) + acc[p][u][nt + 4][reg] + b2l[nt];
          ss += h[nt] * h[nt];
        }
        ss += __shfl_xor(ss, 1, 64); ss += __shfl_xor(ss, 2, 64);
        ss += __shfl_xor(ss, 4, 64); ss += __shfl_xor(ss, 8, 64);
        const float sc = 1.0f / sqrtf(ss);
        const int valid = (vmask >> c) & 1;
#pragma unroll
        for (int nt = 0; nt < 4; nt++) {
          const float o = valid ? h[nt] * sc : truel[nt];
          wsB[U_CE + (v * NC + c) * 64 + nt * 16 + col] = f2b(o);
        }
      }
    }
}

// ---------- var combiner: 32 vars per block, 512 threads ----------
__global__ __launch_bounds__(512) void k_var(
    const void* __restrict__ vars, const void* __restrict__ cval,
    const float* __restrict__ pbuf, const int* __restrict__ flags,
    const u16* __restrict__ wsB, void* __restrict__ outv) {
  __shared__ __align__(16) u16 Xs[32 * 1032];
  __shared__ float ps[32][4];
  __shared__ int hcS[32];

  const int tid = threadIdx.x, lane = tid & 63, wv = tid >> 6;
  const int col = lane & 15, quad = lane >> 4, q8 = quad * 8;
  const int fdt = flags[0], bdt = flags[1];
  const int v0 = blockIdx.x * 32;
  const int mt = wv >> 2, nq = wv & 3;   // m-tile (16 vars), n-quarter (16 d-cols)

  // stage clause_emb rows v0..v0+31 (32 x 1024 bf16), 8 chunks/thread
#pragma unroll
  for (int j = 0; j < 8; j++) {
    const int i = j * 512 + tid;
    const int r = i >> 7, ch = i & 127;
    *(short8*)(Xs + r * 1032 + ch * 8) = *(const short8*)(wsB + U_CE + (v0 + r) * 1024 + ch * 8);
  }
  {
    const int cv = ldmask(cval, v0 * NC + tid, bdt);  // tid -> var tid/16, clause tid%16
    const unsigned long long bal = __ballot(cv != 0);
    const int u = lane >> 4;
    if ((lane & 15) == 0) hcS[wv * 4 + u] = (int)((bal >> (u * 16)) & 0xFFFFull) != 0;
  }
  __syncthreads();

  f32x4 acc1 = (f32x4){0.f, 0.f, 0.f, 0.f}, acc2 = (f32x4){0.f, 0.f, 0.f, 0.f};
#pragma unroll 8
  for (int ks = 0; ks < 32; ks++) {
    const short8 a = *(const short8*)(Xs + (mt * 16 + col) * 1032 + ks * 32 + q8);
    const short8 b1 = *(const short8*)(wsB + U_BC + (nq * 16 + col) * 1024 + ks * 32 + q8);
    const short8 b2 = *(const short8*)(wsB + U_BC + ((nq + 4) * 16 + col) * 1024 + ks * 32 + q8);
    acc1 = __builtin_amdgcn_mfma_f32_16x16x32_bf16(a, b1, acc1, 0, 0, 0);
    acc2 = __builtin_amdgcn_mfma_f32_16x16x32_bf16(a, b2, acc2, 0, 0, 0);
  }

  const int d = nq * 16 + col;
  const float b1c_d = pbuf[PB_B1C + d], b2c_d = pbuf[PB_B2C + d];
  float h[4];
#pragma unroll
  for (int reg = 0; reg < 4; reg++) {
    h[reg] = 1.0f / (1.0f + __expf(-(acc1[reg] + b1c_d))) + acc2[reg] + b2c_d;
    float ssp = h[reg] * h[reg];
    ssp += __shfl_xor(ssp, 1, 64); ssp += __shfl_xor(ssp, 2, 64);
    ssp += __shfl_xor(ssp, 4, 64); ssp += __shfl_xor(ssp, 8, 64);
    if (col == 0) ps[mt * 16 + quad * 4 + reg][nq] = ssp;
  }
  __syncthreads();
#pragma unroll
  for (int reg = 0; reg < 4; reg++) {
    const int r = mt * 16 + quad * 4 + reg;
    const int v = v0 + r;
    const float tot = ps[r][0] + ps[r][1] + ps[r][2] + ps[r][3];
    float o = h[reg] * (1.0f / sqrtf(tot));
    const int oi = v * 64 + d;
    if (hcS[r]) {
      if (fdt) ((u16*)outv)[oi] = f2b(o);
      else ((float*)outv)[oi] = o;
    } else {
      if (fdt) ((u16*)outv)[oi] = ((const u16*)vars)[oi];
      else ((float*)outv)[oi] = ((const float*)vars)[oi];
    }
  }
}

extern "C" void kernel_launch(void* const* d_in, const int* in_sizes, int n_in,
                              void* d_out, int out_size, void* d_ws, size_t ws_size,
                              hipStream_t stream) {
  const void* vars = d_in[0];
  const int* lits = (const int*)d_in[1];
  const void* negm = d_in[2];
  const void* vval = d_in[3];
  const void* cvalid = d_in[4];
  const void* Wn = d_in[5];
  const void* bn = d_in[6];
  const void* femb = d_in[7];
  const void* W1v = d_in[8];
  const void* b1v = d_in[9];
  const void* W2v = d_in[10];
  const void* b2v = d_in[11];
  const void* W1c = d_in[12];
  const void* b1c = d_in[13];
  const void* W2c = d_in[14];
  const void* b2c = d_in[15];

  int* flags = (int*)d_ws;
  float* pbuf = (float*)((char*)d_ws + 256);
  u16* wsB = (u16*)d_ws;

  k_prep<<<2113, 256, 0, stream>>>(vars, lits, negm, vval, Wn, bn, femb,
                                   W1v, b1v, W2v, b2v, W1c, b1c, W2c, b2c,
                                   flags, pbuf, wsB);
  k_negvar<<<(NV + 1 + 63) / 64, 256, 0, stream>>>(pbuf, wsB);
  k_clause<<<NV / 16, 256, 0, stream>>>(cvalid, pbuf, flags, wsB);
  k_var<<<NV / 32, 512, 0, stream>>>(vars, cvalid, pbuf, flags, wsB, d_out);
}

// Round 8
// 168.729 us; speedup vs baseline: 1.2128x; 1.2128x over previous
//
#include <hip/hip_runtime.h>
#include <hip/hip_bf16.h>

#define NV 16384
#define NC 16
#define NL 6
#define ND 64

typedef unsigned short u16;
typedef unsigned int u32;
typedef __attribute__((ext_vector_type(8))) short short8;
typedef __attribute__((ext_vector_type(4))) float f32x4;

// ---- pbuf (fp32) offsets, pbuf = (float*)((char*)ws + 256) ----
#define PB_BN  0
#define PB_FE  64
#define PB_B1V 128
#define PB_B2V 192
#define PB_B1C 256
#define PB_B2C 320
// ---- bf16 regions, offsets in u16 elements from (u16*)ws ----
// BVS: clause-B swizzled [gk(12)][nt(8)][lane(64)][8]; elem = W{1,2}v[k][n&63],
//      k = gk*32 + (lane>>4)*8 + j, n = nt*16 + (lane&15)
#define U_BVS   896       // 49152
// BCS: var-B swizzled [ks(32)][nt(8)][lane(64)][8]
#define U_BCS   50048     // 131072
#define U_BN    181120    // [64][64] Bn[n][k] = Wn[k][n]
#define U_VARSB 185216    // [NV+1][64] bf16 vars; row NV = false_emb
#define U_NEGB  1233856   // [NV+1][64] bf16 negvar; row NV = true_emb
// CES: clause_emb swizzled [v>>4][ks(32)][lane(64)][8]; elem (v,c,d):
//      ks = c*2+(d>>5), lane = ((d>>3)&3)*16 + (v&15), j = d&7
#define U_CES   2282496   // 16777216
#define U_FIDX  19059712  // [NV][96] u16 fused row index (c*6+l)

__device__ __forceinline__ float ldbf(const u16* p, int i) {
  return __uint_as_float(((u32)p[i]) << 16);
}
__device__ __forceinline__ u16 f2b(float f) {  // RNE f32->bf16
  u32 x = __float_as_uint(f);
  return (u16)((x + 0x7FFF + ((x >> 16) & 1)) >> 16);
}
__device__ __forceinline__ int ldmask(const void* p, int i, int bdt) {
  return bdt ? (int)((const signed char*)p)[i] : ((const int*)p)[i];
}
__device__ __forceinline__ float ldf(const void* p, int i, int fdt) {
  return fdt ? ldbf((const u16*)p, i) : ((const float*)p)[i];
}
// async global->LDS, 16 B per lane; LDS dest = uniform base + lane*16
__device__ __forceinline__ void gll16(const u16* g, u16* l) {
  __builtin_amdgcn_global_load_lds(
      (const __attribute__((address_space(1))) u32*)(g),
      (__attribute__((address_space(3))) u32*)(l), 16, 0, 0);
}

// ---------- merged prep ----------
// bid 0: flags+params+BN; 1..24: BVS; 25..88: BCS; 89..600: cvt; 601..2136: fidx
__global__ __launch_bounds__(256) void k_prep(
    const void* vars, const int* __restrict__ lits, const void* negm, const void* vval,
    const void* Wn, const void* bn, const void* femb,
    const void* W1v, const void* b1v, const void* W2v, const void* b2v,
    const void* W1c, const void* b1c, const void* W2c, const void* b2c,
    int* flags, float* pbuf, u16* wsB) {
  __shared__ int s_cnt[4], s_big[4];
  const int t = threadIdx.x;
  {
    const u32 w = ((const u32*)vars)[t];
    const u32 e = (w >> 7) & 0xFF;
    const unsigned long long bal = __ballot(e >= 0x6E && e <= 0x8E);
    const u32 bw = ((const u32*)vval)[t];
    const unsigned long long bb = __ballot(bw > 1u);
    if ((t & 63) == 0) { s_cnt[t >> 6] = __popcll(bal); s_big[t >> 6] = (bb != 0ull); }
  }
  __syncthreads();
  const int fdt = (s_cnt[0] + s_cnt[1] + s_cnt[2] + s_cnt[3]) >= 192;
  const int bdt = (s_big[0] | s_big[1] | s_big[2] | s_big[3]);
  const int bid = blockIdx.x;

  if (bid == 0) {
    if (t == 0) { flags[0] = fdt; flags[1] = bdt; }
    if (t < 64) {
      const void* src[6] = {bn, femb, b1v, b2v, b1c, b2c};
      const int off[6] = {PB_BN, PB_FE, PB_B1V, PB_B2V, PB_B1C, PB_B2C};
      for (int j = 0; j < 6; j++) pbuf[off[j] + t] = ldf(src[j], t, fdt);
      wsB[U_VARSB + NV * 64 + t] = fdt ? ((const u16*)femb)[t] : f2b(((const float*)femb)[t]);
    }
    for (int i = t; i < 4096; i += 256) {
      const int n = i >> 6, k = i & 63;
      wsB[U_BN + i] = f2b(ldf(Wn, k * 64 + n, fdt));
    }
  } else if (bid < 25) {
    const int c = (bid - 1) * 256 + t;            // 0..6143
    const int ln = c & 63, nt = (c >> 6) & 7, ks = c >> 9;  // ks 0..11
    const int n = nt * 16 + (ln & 15);
    const void* src = (n < 64) ? W1v : W2v;
    const int kb = ks * 32 + (ln >> 4) * 8, n6 = n & 63;
    u16 o[8];
#pragma unroll
    for (int j = 0; j < 8; j++) o[j] = f2b(ldf(src, (kb + j) * 64 + n6, fdt));
    *(short8*)(wsB + U_BVS + c * 8) = *(short8*)o;
  } else if (bid < 89) {
    const int c = (bid - 25) * 256 + t;           // 0..16383
    const int ln = c & 63, nt = (c >> 6) & 7, ks = c >> 9;  // ks 0..31
    const int n = nt * 16 + (ln & 15);
    const void* src = (n < 64) ? W1c : W2c;
    const int kb = ks * 32 + (ln >> 4) * 8, n6 = n & 63;
    u16 o[8];
#pragma unroll
    for (int j = 0; j < 8; j++) o[j] = f2b(ldf(src, (kb + j) * 64 + n6, fdt));
    *(short8*)(wsB + U_BCS + c * 8) = *(short8*)o;
  } else if (bid < 601) {
    const int c8 = (bid - 89) * 256 + t;
    u16 o[8];
    if (fdt) {
      *(short8*)o = ((const short8*)vars)[c8];
    } else {
      const float* f = (const float*)vars + c8 * 8;
#pragma unroll
      for (int j = 0; j < 8; j++) o[j] = f2b(f[j]);
    }
    *(short8*)(wsB + U_VARSB + c8 * 8) = *(short8*)o;
  } else {
    const int i0 = ((bid - 601) * 256 + t) * 4;
    u16 o[4];
#pragma unroll
    for (int j = 0; j < 4; j++) {
      const int i = i0 + j;
      const int valid = ldmask(vval, i, bdt);
      const int neg = ldmask(negm, i, bdt);
      const int idx = lits[i];
      o[j] = (u16)(valid ? (idx + (neg ? (NV + 1) : 0)) : NV);
    }
    *(ushort4*)(wsB + U_FIDX + i0) = *(ushort4*)o;
  }
}

// ---------- negvar via MFMA ----------
__global__ __launch_bounds__(256) void k_negvar(const float* pbuf, u16* wsB) {
  const int tid = threadIdx.x, lane = tid & 63, wv = tid >> 6;
  const int col = lane & 15, quad = lane >> 4, q8 = quad * 8;
  const int rowbase = blockIdx.x * 64 + wv * 16;
  f32x4 acc[4];
#pragma unroll
  for (int nt = 0; nt < 4; nt++) acc[nt] = (f32x4){0.f, 0.f, 0.f, 0.f};
  const int arow = min(rowbase + col, NV);
#pragma unroll
  for (int ks = 0; ks < 2; ks++) {
    const short8 a = *(const short8*)(wsB + U_VARSB + arow * 64 + ks * 32 + q8);
#pragma unroll
    for (int nt = 0; nt < 4; nt++) {
      const short8 b = *(const short8*)(wsB + U_BN + (nt * 16 + col) * 64 + ks * 32 + q8);
      acc[nt] = __builtin_amdgcn_mfma_f32_16x16x32_bf16(a, b, acc[nt], 0, 0, 0);
    }
  }
#pragma unroll
  for (int reg = 0; reg < 4; reg++) {
    const int r = rowbase + quad * 4 + reg;
    if (r <= NV) {
#pragma unroll
      for (int nt = 0; nt < 4; nt++) {
        const int d = nt * 16 + col;
        wsB[U_NEGB + r * 64 + d] = f2b(acc[nt][reg] + pbuf[PB_BN + d]);
      }
    }
  }
}

// ---------- clause combiner: gll-staged swizzled B, reg-gathered A, 4 vars/wave ----------
__global__ __launch_bounds__(256, 2) void k_clause(
    const void* __restrict__ cval, const float* __restrict__ pbuf,
    const int* __restrict__ flags, u16* __restrict__ wsB) {
  __shared__ __align__(16) u16 Bs[2][12288];  // [buf][(ksl*8+nt)*512 + lane*8] = 2x24 KB

  const int tid = threadIdx.x, lane = tid & 63, wv = tid >> 6;
  const int col = lane & 15, quad = lane >> 4, q8 = quad * 8;
  const int bdt = flags[1];
  const int vbase = (blockIdx.x * 4 + wv) * 4;

  // packed fidx: r2_[v4][i] holds literals 2i,2i+1 of clause `col` of var vbase+v4
  u32 r2_[4][3];
#pragma unroll
  for (int v4 = 0; v4 < 4; v4++)
#pragma unroll
    for (int i = 0; i < 3; i++)
      r2_[4 > v4 ? v4 : 0][i] = *(const u32*)(wsB + U_FIDX + (vbase + v4) * 96 + col * 6 + i * 2);

  const int cv = ldmask(cval, vbase * 16 + lane, bdt);
  const unsigned long long bal = __ballot(cv != 0);

  f32x4 acc[4][8];
#pragma unroll
  for (int v4 = 0; v4 < 4; v4++)
#pragma unroll
    for (int nt = 0; nt < 8; nt++) acc[v4][nt] = (f32x4){0.f, 0.f, 0.f, 0.f};

  // stage quarter 0 into buf 0 (6 chunks of 1 KB per wave)
#pragma unroll
  for (int j = 0; j < 6; j++) {
    const int cl = wv * 6 + j;
    gll16(wsB + U_BVS + cl * 512 + lane * 8, &Bs[0][cl * 512]);
  }
  // prefetch A for gk=0 (literal 0, low half)
  short8 a_cur[4], a_nxt[4];
#pragma unroll
  for (int v4 = 0; v4 < 4; v4++) {
    const int idx = (int)(r2_[v4][0] & 0xFFFFu);
    a_cur[v4] = *(const short8*)(wsB + U_VARSB + idx * 64 + q8);
  }
  __syncthreads();

  for (int q = 0; q < 4; q++) {
    if (q < 3) {
#pragma unroll
      for (int j = 0; j < 6; j++) {
        const int cl = wv * 6 + j;
        gll16(wsB + U_BVS + (q + 1) * 12288 + cl * 512 + lane * 8, &Bs[(q + 1) & 1][cl * 512]);
      }
    }
#pragma unroll
    for (int ksl = 0; ksl < 3; ksl++) {
      const int gk = q * 3 + ksl;
      if (gk < 11) {
        const int gn = gk + 1;
        const int goff = (gn & 1) * 32 + q8;
        const int pi = gn >> 2, ph = (gn >> 1) & 1;
#pragma unroll
        for (int v4 = 0; v4 < 4; v4++) {
          const int idx = (int)((r2_[v4][pi] >> (ph * 16)) & 0xFFFFu);
          a_nxt[v4] = *(const short8*)(wsB + U_VARSB + idx * 64 + goff);
        }
      }
#pragma unroll
      for (int nt = 0; nt < 8; nt++) {
        const short8 b = *(const short8*)(&Bs[q & 1][(ksl * 8 + nt) * 512 + lane * 8]);
#pragma unroll
        for (int v4 = 0; v4 < 4; v4++)
          acc[v4][nt] = __builtin_amdgcn_mfma_f32_16x16x32_bf16(a_cur[v4], b, acc[v4][nt], 0, 0, 0);
      }
#pragma unroll
      for (int v4 = 0; v4 < 4; v4++) a_cur[v4] = a_nxt[v4];
    }
    if (q < 3) __syncthreads();
  }

  // epilogue -> swizzled CES
  float b1l[4], b2l[4], truel[4];
#pragma unroll
  for (int nt = 0; nt < 4; nt++) {
    const int d = nt * 16 + col;
    b1l[nt] = pbuf[PB_B1V + d];
    b2l[nt] = pbuf[PB_B2V + d];
    truel[nt] = ldbf(wsB, U_NEGB + NV * 64 + d);
  }
#pragma unroll
  for (int v4 = 0; v4 < 4; v4++) {
    const u32 vmask = (u32)((bal >> (v4 * 16)) & 0xFFFFull);
    const int vloc = wv * 4 + v4;
#pragma unroll
    for (int reg = 0; reg < 4; reg++) {
      const int c = quad * 4 + reg;
      float hh[4], ss = 0.f;
#pragma unroll
      for (int nt = 0; nt < 4; nt++) {
        hh[nt] = 1.0f / (1.0f + __expf(-(acc[v4][nt][reg] + b1l[nt]))) + acc[v4][nt + 4][reg] + b2l[nt];
        ss += hh[nt] * hh[nt];
      }
      ss += __shfl_xor(ss, 1, 64); ss += __shfl_xor(ss, 2, 64);
      ss += __shfl_xor(ss, 4, 64); ss += __shfl_xor(ss, 8, 64);
      const float sc = 1.0f / sqrtf(ss);
      const int valid = (vmask >> c) & 1;
#pragma unroll
      for (int nt = 0; nt < 4; nt++) {
        const float o = valid ? hh[nt] * sc : truel[nt];
        const int l2 = (nt * 2 + (col >> 3)) & 3;
        wsB[U_CES + ((blockIdx.x * 32 + c * 2 + (nt >> 1)) * 64 + l2 * 16 + vloc) * 8 + (col & 7)] = f2b(o);
      }
    }
  }
}

// ---------- var combiner: 32 vars/block, gll-staged swizzled A ----------
__global__ __launch_bounds__(512) void k_var(
    const void* __restrict__ vars, const void* __restrict__ cval,
    const float* __restrict__ pbuf, const int* __restrict__ flags,
    const u16* __restrict__ wsB, void* __restrict__ outv) {
  __shared__ __align__(16) u16 Xs[32768];  // [grp(2)][ks(32)][lane(64)][8] = 64 KB
  __shared__ float ps[32][4];
  __shared__ int hcS[32];

  const int tid = threadIdx.x, lane = tid & 63, wv = tid >> 6;
  const int col = lane & 15, quad = lane >> 4;
  const int fdt = flags[0], bdt = flags[1];
  const int v0 = blockIdx.x * 32;
  const int mt = wv >> 2, nq = wv & 3;

  // stage 64 KB of swizzled clause_emb (8 chunks/wave)
#pragma unroll
  for (int j = 0; j < 8; j++) {
    const int c = wv * 8 + j;
    gll16(wsB + U_CES + blockIdx.x * 32768 + c * 512 + lane * 8, &Xs[c * 512]);
  }
  {
    const int cv = ldmask(cval, v0 * NC + tid, bdt);
    const unsigned long long bal = __ballot(cv != 0);
    const int u = lane >> 4;
    if ((lane & 15) == 0) hcS[wv * 4 + u] = (int)((bal >> (u * 16)) & 0xFFFFull) != 0;
  }
  __syncthreads();

  f32x4 acc1 = (f32x4){0.f, 0.f, 0.f, 0.f}, acc2 = (f32x4){0.f, 0.f, 0.f, 0.f};
#pragma unroll 8
  for (int ks = 0; ks < 32; ks++) {
    const short8 a = *(const short8*)(&Xs[(mt * 32 + ks) * 512 + lane * 8]);
    const short8 b1 = *(const short8*)(wsB + U_BCS + (ks * 8 + nq) * 512 + lane * 8);
    const short8 b2 = *(const short8*)(wsB + U_BCS + (ks * 8 + nq + 4) * 512 + lane * 8);
    acc1 = __builtin_amdgcn_mfma_f32_16x16x32_bf16(a, b1, acc1, 0, 0, 0);
    acc2 = __builtin_amdgcn_mfma_f32_16x16x32_bf16(a, b2, acc2, 0, 0, 0);
  }

  const int d = nq * 16 + col;
  const float b1c_d = pbuf[PB_B1C + d], b2c_d = pbuf[PB_B2C + d];
  float h[4];
#pragma unroll
  for (int reg = 0; reg < 4; reg++) {
    h[reg] = 1.0f / (1.0f + __expf(-(acc1[reg] + b1c_d))) + acc2[reg] + b2c_d;
    float ssp = h[reg] * h[reg];
    ssp += __shfl_xor(ssp, 1, 64); ssp += __shfl_xor(ssp, 2, 64);
    ssp += __shfl_xor(ssp, 4, 64); ssp += __shfl_xor(ssp, 8, 64);
    if (col == 0) ps[mt * 16 + quad * 4 + reg][nq] = ssp;
  }
  __syncthreads();
#pragma unroll
  for (int reg = 0; reg < 4; reg++) {
    const int r = mt * 16 + quad * 4 + reg;
    const int v = v0 + r;
    const float tot = ps[r][0] + ps[r][1] + ps[r][2] + ps[r][3];
    float o = h[reg] * (1.0f / sqrtf(tot));
    const int oi = v * 64 + d;
    if (hcS[r]) {
      if (fdt) ((u16*)outv)[oi] = f2b(o);
      else ((float*)outv)[oi] = o;
    } else {
      if (fdt) ((u16*)outv)[oi] = ((const u16*)vars)[oi];
      else ((float*)outv)[oi] = ((const float*)vars)[oi];
    }
  }
}

extern "C" void kernel_launch(void* const* d_in, const int* in_sizes, int n_in,
                              void* d_out, int out_size, void* d_ws, size_t ws_size,
                              hipStream_t stream) {
  const void* vars = d_in[0];
  const int* lits = (const int*)d_in[1];
  const void* negm = d_in[2];
  const void* vval = d_in[3];
  const void* cvalid = d_in[4];
  const void* Wn = d_in[5];
  const void* bn = d_in[6];
  const void* femb = d_in[7];
  const void* W1v = d_in[8];
  const void* b1v = d_in[9];
  const void* W2v = d_in[10];
  const void* b2v = d_in[11];
  const void* W1c = d_in[12];
  const void* b1c = d_in[13];
  const void* W2c = d_in[14];
  const void* b2c = d_in[15];

  int* flags = (int*)d_ws;
  float* pbuf = (float*)((char*)d_ws + 256);
  u16* wsB = (u16*)d_ws;

  k_prep<<<2137, 256, 0, stream>>>(vars, lits, negm, vval, Wn, bn, femb,
                                   W1v, b1v, W2v, b2v, W1c, b1c, W2c, b2c,
                                   flags, pbuf, wsB);
  k_negvar<<<(NV + 1 + 63) / 64, 256, 0, stream>>>(pbuf, wsB);
  k_clause<<<NV / 16, 256, 0, stream>>>(cvalid, pbuf, flags, wsB);
  k_var<<<NV / 32, 512, 0, stream>>>(vars, cvalid, pbuf, flags, wsB, d_out);
}

// Round 9
// 158.335 us; speedup vs baseline: 1.2924x; 1.0656x over previous
//
#include <hip/hip_runtime.h>
#include <hip/hip_bf16.h>

#define NV 16384
#define NC 16
#define NL 6
#define ND 64

typedef unsigned short u16;
typedef unsigned int u32;
typedef __attribute__((ext_vector_type(8))) short short8;
typedef __attribute__((ext_vector_type(4))) float f32x4;

// ---- pbuf (fp32) offsets, pbuf = (float*)((char*)ws + 256) ----
#define PB_BN  0
#define PB_FE  64
#define PB_B1V 128
#define PB_B2V 192
#define PB_B1C 256
#define PB_B2C 320
// ---- bf16 regions, offsets in u16 elements from (u16*)ws ----
// BVS: clause-B swizzled [gk(12)][nt(8)][lane(64)][8]; elem = W{1,2}v[k][n&63],
//      k = gk*32 + (lane>>4)*8 + j, n = nt*16 + (lane&15)
#define U_BVS   896       // 49152
// BCS: var-B swizzled [ks(32)][nt(8)][lane(64)][8]
#define U_BCS   50048     // 131072
#define U_BN    181120    // [64][64] Bn[n][k] = Wn[k][n]
#define U_VARSB 185216    // [NV+1][64] bf16 vars; row NV = false_emb
#define U_NEGB  1233856   // [NV+1][64] bf16 negvar; row NV = true_emb
#define U_FIDX  2282496   // [NV][96] u16 fused row index (c*6+l)

__device__ __forceinline__ float ldbf(const u16* p, int i) {
  return __uint_as_float(((u32)p[i]) << 16);
}
__device__ __forceinline__ u16 f2b(float f) {  // RNE f32->bf16
  u32 x = __float_as_uint(f);
  return (u16)((x + 0x7FFF + ((x >> 16) & 1)) >> 16);
}
__device__ __forceinline__ int ldmask(const void* p, int i, int bdt) {
  return bdt ? (int)((const signed char*)p)[i] : ((const int*)p)[i];
}
__device__ __forceinline__ float ldf(const void* p, int i, int fdt) {
  return fdt ? ldbf((const u16*)p, i) : ((const float*)p)[i];
}
// async global->LDS, 16 B per lane; LDS dest = uniform base + lane*16
__device__ __forceinline__ void gll16(const u16* g, u16* l) {
  __builtin_amdgcn_global_load_lds(
      (const __attribute__((address_space(1))) u32*)(g),
      (__attribute__((address_space(3))) u32*)(l), 16, 0, 0);
}

// ---------- merged prep ----------
// bid 0: flags+params+BN; 1..24: BVS; 25..88: BCS; 89..600: cvt; 601..2136: fidx
__global__ __launch_bounds__(256) void k_prep(
    const void* vars, const int* __restrict__ lits, const void* negm, const void* vval,
    const void* Wn, const void* bn, const void* femb,
    const void* W1v, const void* b1v, const void* W2v, const void* b2v,
    const void* W1c, const void* b1c, const void* W2c, const void* b2c,
    int* flags, float* pbuf, u16* wsB) {
  __shared__ int s_cnt[4], s_big[4];
  const int t = threadIdx.x;
  {
    const u32 w = ((const u32*)vars)[t];
    const u32 e = (w >> 7) & 0xFF;
    const unsigned long long bal = __ballot(e >= 0x6E && e <= 0x8E);
    const u32 bw = ((const u32*)vval)[t];
    const unsigned long long bb = __ballot(bw > 1u);
    if ((t & 63) == 0) { s_cnt[t >> 6] = __popcll(bal); s_big[t >> 6] = (bb != 0ull); }
  }
  __syncthreads();
  const int fdt = (s_cnt[0] + s_cnt[1] + s_cnt[2] + s_cnt[3]) >= 192;
  const int bdt = (s_big[0] | s_big[1] | s_big[2] | s_big[3]);
  const int bid = blockIdx.x;

  if (bid == 0) {
    if (t == 0) { flags[0] = fdt; flags[1] = bdt; }
    if (t < 64) {
      const void* src[6] = {bn, femb, b1v, b2v, b1c, b2c};
      const int off[6] = {PB_BN, PB_FE, PB_B1V, PB_B2V, PB_B1C, PB_B2C};
      for (int j = 0; j < 6; j++) pbuf[off[j] + t] = ldf(src[j], t, fdt);
      wsB[U_VARSB + NV * 64 + t] = fdt ? ((const u16*)femb)[t] : f2b(((const float*)femb)[t]);
    }
    for (int i = t; i < 4096; i += 256) {
      const int n = i >> 6, k = i & 63;
      wsB[U_BN + i] = f2b(ldf(Wn, k * 64 + n, fdt));
    }
  } else if (bid < 25) {
    const int c = (bid - 1) * 256 + t;            // 0..6143
    const int ln = c & 63, nt = (c >> 6) & 7, ks = c >> 9;  // ks 0..11
    const int n = nt * 16 + (ln & 15);
    const void* src = (n < 64) ? W1v : W2v;
    const int kb = ks * 32 + (ln >> 4) * 8, n6 = n & 63;
    u16 o[8];
#pragma unroll
    for (int j = 0; j < 8; j++) o[j] = f2b(ldf(src, (kb + j) * 64 + n6, fdt));
    *(short8*)(wsB + U_BVS + c * 8) = *(short8*)o;
  } else if (bid < 89) {
    const int c = (bid - 25) * 256 + t;           // 0..16383
    const int ln = c & 63, nt = (c >> 6) & 7, ks = c >> 9;  // ks 0..31
    const int n = nt * 16 + (ln & 15);
    const void* src = (n < 64) ? W1c : W2c;
    const int kb = ks * 32 + (ln >> 4) * 8, n6 = n & 63;
    u16 o[8];
#pragma unroll
    for (int j = 0; j < 8; j++) o[j] = f2b(ldf(src, (kb + j) * 64 + n6, fdt));
    *(short8*)(wsB + U_BCS + c * 8) = *(short8*)o;
  } else if (bid < 601) {
    const int c8 = (bid - 89) * 256 + t;
    u16 o[8];
    if (fdt) {
      *(short8*)o = ((const short8*)vars)[c8];
    } else {
      const float* f = (const float*)vars + c8 * 8;
#pragma unroll
      for (int j = 0; j < 8; j++) o[j] = f2b(f[j]);
    }
    *(short8*)(wsB + U_VARSB + c8 * 8) = *(short8*)o;
  } else {
    const int i0 = ((bid - 601) * 256 + t) * 4;
    u16 o[4];
#pragma unroll
    for (int j = 0; j < 4; j++) {
      const int i = i0 + j;
      const int valid = ldmask(vval, i, bdt);
      const int neg = ldmask(negm, i, bdt);
      const int idx = lits[i];
      o[j] = (u16)(valid ? (idx + (neg ? (NV + 1) : 0)) : NV);
    }
    *(ushort4*)(wsB + U_FIDX + i0) = *(ushort4*)o;
  }
}

// ---------- negvar via MFMA ----------
__global__ __launch_bounds__(256) void k_negvar(const float* pbuf, u16* wsB) {
  const int tid = threadIdx.x, lane = tid & 63, wv = tid >> 6;
  const int col = lane & 15, quad = lane >> 4, q8 = quad * 8;
  const int rowbase = blockIdx.x * 64 + wv * 16;
  f32x4 acc[4];
#pragma unroll
  for (int nt = 0; nt < 4; nt++) acc[nt] = (f32x4){0.f, 0.f, 0.f, 0.f};
  const int arow = min(rowbase + col, NV);
#pragma unroll
  for (int ks = 0; ks < 2; ks++) {
    const short8 a = *(const short8*)(wsB + U_VARSB + arow * 64 + ks * 32 + q8);
#pragma unroll
    for (int nt = 0; nt < 4; nt++) {
      const short8 b = *(const short8*)(wsB + U_BN + (nt * 16 + col) * 64 + ks * 32 + q8);
      acc[nt] = __builtin_amdgcn_mfma_f32_16x16x32_bf16(a, b, acc[nt], 0, 0, 0);
    }
  }
#pragma unroll
  for (int reg = 0; reg < 4; reg++) {
    const int r = rowbase + quad * 4 + reg;
    if (r <= NV) {
#pragma unroll
      for (int nt = 0; nt < 4; nt++) {
        const int d = nt * 16 + col;
        wsB[U_NEGB + r * 64 + d] = f2b(acc[nt][reg] + pbuf[PB_BN + d]);
      }
    }
  }
}

// ---------- fused clause + var combiner: 16 vars/block, 256 threads ----------
__global__ __launch_bounds__(256, 2) void k_main(
    const void* __restrict__ vars, const void* __restrict__ cval,
    const float* __restrict__ pbuf, const int* __restrict__ flags,
    const u16* __restrict__ wsB, void* __restrict__ outv) {
  // phase 1: smem = B double-buffer [2][12288] (48 KB)
  // phase 2: smem[0..16383] = clause_emb swizzled [ks(32)][lane(64)][8] (32 KB)
  __shared__ __align__(16) u16 smem[24576];
  __shared__ float ps[16][4];
  __shared__ int hcS[16];

  const int tid = threadIdx.x, lane = tid & 63, wv = tid >> 6;
  const int col = lane & 15, quad = lane >> 4, q8 = quad * 8;
  const int fdt = flags[0], bdt = flags[1];
  const int vbase = (blockIdx.x * 4 + wv) * 4;
  const int v0 = blockIdx.x * 16;

  // packed fidx: r2_[v4][i] = literals 2i,2i+1 of clause `col` of var vbase+v4
  u32 r2_[4][3];
#pragma unroll
  for (int v4 = 0; v4 < 4; v4++)
#pragma unroll
    for (int i = 0; i < 3; i++)
      r2_[v4][i] = *(const u32*)(wsB + U_FIDX + (vbase + v4) * 96 + col * 6 + i * 2);

  const int cv = ldmask(cval, vbase * 16 + lane, bdt);
  const unsigned long long bal = __ballot(cv != 0);
  if (lane < 4) hcS[wv * 4 + lane] = ((bal >> (lane * 16)) & 0xFFFFull) != 0;

  f32x4 acc[4][8];
#pragma unroll
  for (int v4 = 0; v4 < 4; v4++)
#pragma unroll
    for (int nt = 0; nt < 8; nt++) acc[v4][nt] = (f32x4){0.f, 0.f, 0.f, 0.f};

  // stage quarter 0 into buf 0 (6 chunks of 1 KB per wave)
#pragma unroll
  for (int j = 0; j < 6; j++) {
    const int cl = wv * 6 + j;
    gll16(wsB + U_BVS + cl * 512 + lane * 8, &smem[cl * 512]);
  }
  // prefetch A for gk=0
  short8 a_cur[4], a_nxt[4];
#pragma unroll
  for (int v4 = 0; v4 < 4; v4++) {
    const int idx = (int)(r2_[v4][0] & 0xFFFFu);
    a_cur[v4] = *(const short8*)(wsB + U_VARSB + idx * 64 + q8);
  }
  __syncthreads();

  for (int q = 0; q < 4; q++) {
    if (q < 3) {
#pragma unroll
      for (int j = 0; j < 6; j++) {
        const int cl = wv * 6 + j;
        gll16(wsB + U_BVS + (q + 1) * 12288 + cl * 512 + lane * 8,
              &smem[((q + 1) & 1) * 12288 + cl * 512]);
      }
    }
#pragma unroll
    for (int ksl = 0; ksl < 3; ksl++) {
      const int gk = q * 3 + ksl;
      if (gk < 11) {
        const int gn = gk + 1;
        const int goff = (gn & 1) * 32 + q8;
        const int pi = gn >> 2, ph = (gn >> 1) & 1;
#pragma unroll
        for (int v4 = 0; v4 < 4; v4++) {
          const int idx = (int)((r2_[v4][pi] >> (ph * 16)) & 0xFFFFu);
          a_nxt[v4] = *(const short8*)(wsB + U_VARSB + idx * 64 + goff);
        }
      }
#pragma unroll
      for (int nt = 0; nt < 8; nt++) {
        const short8 b = *(const short8*)(&smem[(q & 1) * 12288 + (ksl * 8 + nt) * 512 + lane * 8]);
#pragma unroll
        for (int v4 = 0; v4 < 4; v4++)
          acc[v4][nt] = __builtin_amdgcn_mfma_f32_16x16x32_bf16(a_cur[v4], b, acc[v4][nt], 0, 0, 0);
      }
#pragma unroll
      for (int v4 = 0; v4 < 4; v4++) a_cur[v4] = a_nxt[v4];
    }
    if (q < 3) __syncthreads();
  }
  __syncthreads();  // all waves done reading B before epilogue overwrites smem

  // phase-1 epilogue: normalize, clause-pad, write into smem (A-swizzled for phase 2)
  {
    float b1l[4], b2l[4], truel[4];
#pragma unroll
    for (int nt = 0; nt < 4; nt++) {
      const int d = nt * 16 + col;
      b1l[nt] = pbuf[PB_B1V + d];
      b2l[nt] = pbuf[PB_B2V + d];
      truel[nt] = ldbf(wsB, U_NEGB + NV * 64 + d);
    }
#pragma unroll
    for (int v4 = 0; v4 < 4; v4++) {
      const u32 vmask = (u32)((bal >> (v4 * 16)) & 0xFFFFull);
      const int vloc = wv * 4 + v4;
#pragma unroll
      for (int reg = 0; reg < 4; reg++) {
        const int c = quad * 4 + reg;
        float hh[4], ss = 0.f;
#pragma unroll
        for (int nt = 0; nt < 4; nt++) {
          hh[nt] = 1.0f / (1.0f + __expf(-(acc[v4][nt][reg] + b1l[nt]))) + acc[v4][nt + 4][reg] + b2l[nt];
          ss += hh[nt] * hh[nt];
        }
        ss += __shfl_xor(ss, 1, 64); ss += __shfl_xor(ss, 2, 64);
        ss += __shfl_xor(ss, 4, 64); ss += __shfl_xor(ss, 8, 64);
        const float sc = 1.0f / sqrtf(ss);
        const int valid = (vmask >> c) & 1;
#pragma unroll
        for (int nt = 0; nt < 4; nt++) {
          const float o = valid ? hh[nt] * sc : truel[nt];
          const int l2 = (nt * 2 + (col >> 3)) & 3;
          smem[(c * 2 + (nt >> 1)) * 512 + (l2 * 16 + vloc) * 8 + (col & 7)] = f2b(o);
        }
      }
    }
  }
  __syncthreads();

  // phase 2: var combiner. M=16 (block's vars), K=1024, wave wv -> d cols [wv*16, wv*16+16)
  f32x4 acc1 = (f32x4){0.f, 0.f, 0.f, 0.f}, acc2 = (f32x4){0.f, 0.f, 0.f, 0.f};
#pragma unroll 8
  for (int ks = 0; ks < 32; ks++) {
    const short8 a = *(const short8*)(&smem[ks * 512 + lane * 8]);
    const short8 b1 = *(const short8*)(wsB + U_BCS + (ks * 8 + wv) * 512 + lane * 8);
    const short8 b2 = *(const short8*)(wsB + U_BCS + (ks * 8 + wv + 4) * 512 + lane * 8);
    acc1 = __builtin_amdgcn_mfma_f32_16x16x32_bf16(a, b1, acc1, 0, 0, 0);
    acc2 = __builtin_amdgcn_mfma_f32_16x16x32_bf16(a, b2, acc2, 0, 0, 0);
  }

  const int d = wv * 16 + col;
  const float b1c_d = pbuf[PB_B1C + d], b2c_d = pbuf[PB_B2C + d];
  float h[4];
#pragma unroll
  for (int reg = 0; reg < 4; reg++) {
    h[reg] = 1.0f / (1.0f + __expf(-(acc1[reg] + b1c_d))) + acc2[reg] + b2c_d;
    float ssp = h[reg] * h[reg];
    ssp += __shfl_xor(ssp, 1, 64); ssp += __shfl_xor(ssp, 2, 64);
    ssp += __shfl_xor(ssp, 4, 64); ssp += __shfl_xor(ssp, 8, 64);
    if (col == 0) ps[quad * 4 + reg][wv] = ssp;
  }
  __syncthreads();
#pragma unroll
  for (int reg = 0; reg < 4; reg++) {
    const int r = quad * 4 + reg;
    const float tot = ps[r][0] + ps[r][1] + ps[r][2] + ps[r][3];
    float o = h[reg] * (1.0f / sqrtf(tot));
    const int oi = (v0 + r) * 64 + d;
    if (hcS[r]) {
      if (fdt) ((u16*)outv)[oi] = f2b(o);
      else ((float*)outv)[oi] = o;
    } else {
      if (fdt) ((u16*)outv)[oi] = ((const u16*)vars)[oi];
      else ((float*)outv)[oi] = ((const float*)vars)[oi];
    }
  }
}

extern "C" void kernel_launch(void* const* d_in, const int* in_sizes, int n_in,
                              void* d_out, int out_size, void* d_ws, size_t ws_size,
                              hipStream_t stream) {
  const void* vars = d_in[0];
  const int* lits = (const int*)d_in[1];
  const void* negm = d_in[2];
  const void* vval = d_in[3];
  const void* cvalid = d_in[4];
  const void* Wn = d_in[5];
  const void* bn = d_in[6];
  const void* femb = d_in[7];
  const void* W1v = d_in[8];
  const void* b1v = d_in[9];
  const void* W2v = d_in[10];
  const void* b2v = d_in[11];
  const void* W1c = d_in[12];
  const void* b1c = d_in[13];
  const void* W2c = d_in[14];
  const void* b2c = d_in[15];

  int* flags = (int*)d_ws;
  float* pbuf = (float*)((char*)d_ws + 256);
  u16* wsB = (u16*)d_ws;

  k_prep<<<2137, 256, 0, stream>>>(vars, lits, negm, vval, Wn, bn, femb,
                                   W1v, b1v, W2v, b2v, W1c, b1c, W2c, b2c,
                                   flags, pbuf, wsB);
  k_negvar<<<(NV + 1 + 63) / 64, 256, 0, stream>>>(pbuf, wsB);
  k_main<<<NV / 16, 256, 0, stream>>>(vars, cvalid, pbuf, flags, wsB, d_out);
}